// Round 11
// baseline (51.622 us; speedup 1.0000x reference)
//
#include <hip/hip_runtime.h>

#define NS 32
#define GD 10
#define NC3 (GD * GD * GD)
#define NPB 4096          // points per batch (fast path requires n == NPB)
#define INV_CELL 0.5f
#define MARGIN 1e-3f

// ---------------------------------------------------------------------------
// K1: fused bin + per-cell sort, one block per batch, entirely in LDS.
// Produces a compact CSR: cellStart[b*NC3 + c] (global prefix, sentinel at
// nb*NC3) and pts[] (float4 = x,y,z,local_idx), index-sorted within each
// cell. Deterministic: LDS-atomic scatter order is erased by the in-LDS
// insertion sort, so the table is a pure function of the inputs (harness
// graph-replays and re-validates; no memset dispatch needed).
// ---------------------------------------------------------------------------
__global__ __launch_bounds__(256) void bin_sort_kernel(
    const float* __restrict__ xyz, int n, int nb,
    int* __restrict__ cellStart, float4* __restrict__ pts)
{
    __shared__ int    lcnt[NC3];     // 4 KB
    __shared__ int    lpref[NC3];    // 4 KB (exclusive prefix)
    __shared__ int    lcur[NC3];     // 4 KB (scatter cursors)
    __shared__ float4 lpts[NPB];     // 64 KB
    __shared__ int    wsum[4];

    const int tid = threadIdx.x;
    const int b   = blockIdx.x;
    const float* __restrict__ px = xyz + (size_t)b * n * 3;

    for (int c = tid; c < NC3; c += 256) lcnt[c] = 0;
    __syncthreads();

    // count (x*0.5f and floorf are exact for the cell assignment)
    for (int i = tid; i < n; i += 256) {
        float x = px[3 * i], y = px[3 * i + 1], z = px[3 * i + 2];
        int cx = min(max((int)floorf(x * INV_CELL), 0), GD - 1);
        int cy = min(max((int)floorf(y * INV_CELL), 0), GD - 1);
        int cz = min(max((int)floorf(z * INV_CELL), 0), GD - 1);
        atomicAdd(&lcnt[(cx * GD + cy) * GD + cz], 1);
    }
    __syncthreads();

    // block-wide exclusive scan over NC3 cells (4 cells/thread)
    const int base = tid * 4;
    int c0 = 0, c1 = 0, c2 = 0, c3 = 0, tt = 0;
    if (base < NC3) {
        c0 = lcnt[base];
        c1 = base + 1 < NC3 ? lcnt[base + 1] : 0;
        c2 = base + 2 < NC3 ? lcnt[base + 2] : 0;
        c3 = base + 3 < NC3 ? lcnt[base + 3] : 0;
        tt = c0 + c1 + c2 + c3;
    }
    const int lane = tid & 63, wv = tid >> 6;
    int run = tt;
    #pragma unroll
    for (int off = 1; off < 64; off <<= 1) {
        int y = __shfl_up(run, off, 64);
        if (lane >= off) run += y;
    }
    if (lane == 63) wsum[wv] = run;
    __syncthreads();
    int woff = 0;
    for (int w = 0; w < wv; ++w) woff += wsum[w];
    const int excl = woff + run - tt;
    if (base < NC3) {
        lpref[base] = excl;
        if (base + 1 < NC3) lpref[base + 1] = excl + c0;
        if (base + 2 < NC3) lpref[base + 2] = excl + c0 + c1;
        if (base + 3 < NC3) lpref[base + 3] = excl + c0 + c1 + c2;
    }
    __syncthreads();
    for (int c = tid; c < NC3; c += 256) lcur[c] = lpref[c];
    __syncthreads();

    // scatter (LDS atomics; order nondeterministic, fixed by sort below)
    for (int i = tid; i < n; i += 256) {
        float x = px[3 * i], y = px[3 * i + 1], z = px[3 * i + 2];
        int cx = min(max((int)floorf(x * INV_CELL), 0), GD - 1);
        int cy = min(max((int)floorf(y * INV_CELL), 0), GD - 1);
        int cz = min(max((int)floorf(z * INV_CELL), 0), GD - 1);
        int pos = atomicAdd(&lcur[(cx * GD + cy) * GD + cz], 1);
        lpts[pos] = make_float4(x, y, z, __int_as_float(i));
    }
    __syncthreads();

    // per-cell insertion sort by local idx (cells are small: lambda ~ 4)
    #pragma unroll
    for (int k = 0; k < 4; ++k) {
        const int c = base + k;
        if (c >= NC3) break;
        const int s = lpref[c];
        const int e = (c + 1 < NC3) ? lpref[c + 1] : n;
        for (int i = s + 1; i < e; ++i) {
            float4 key = lpts[i];
            int kk = __float_as_int(key.w);
            int j = i - 1;
            while (j >= s && __float_as_int(lpts[j].w) > kk) {
                lpts[j + 1] = lpts[j];
                --j;
            }
            lpts[j + 1] = key;
        }
    }
    __syncthreads();

    // write out CSR
    for (int i = tid; i < n; i += 256) pts[(size_t)b * n + i] = lpts[i];
    for (int c = tid; c < NC3; c += 256) cellStart[b * NC3 + c] = b * n + lpref[c];
    if (b == nb - 1 && tid == 0) cellStart[nb * NC3] = nb * n;
}

// ---------------------------------------------------------------------------
// K2: fused query + weight + grouped relation. One wave per query.
//  1. neighbor region = nx*ny <= 16 CONTIGUOUS z-column ranges in the CSR
//     (z-cells are adjacent); lanes 0..nrange-1 load [start,end) in parallel;
//     64-wide shfl-scan; 17-entry prefix + 16 bases -> LDS.
//  [barrier]
//  2. scan ceil(T/64) chunks; lane -> (range, slot) via 4-step binary search
//     over the prefix; float4 gather -> d2 -> ballot-compact hits.
//  [barrier]
//  3. bitonic sort ascending (width-32 fast path when tot <= 32, uniform
//     branch) -> first 32 by index; pad with first; n-1 row if none.
//  4. lanes 0-31 emit pred relation (+weights), lanes 32-63 tgt relation.
// ---------------------------------------------------------------------------
template <int C>
__global__ __launch_bounds__(256) void query_kernel(
    const float* __restrict__ new_xyz,
    const float* __restrict__ pred, const float* __restrict__ tgt,
    const int* __restrict__ cellStart, const float4* __restrict__ pts,
    int n, int total,
    float* __restrict__ out0, float* __restrict__ out1, float* __restrict__ wout)
{
#pragma clang fp contract(off)
    __shared__ int spref[4][17];
    __shared__ int sgb[4][16];
    __shared__ int slist[4][64];

    const int lane = threadIdx.x & 63;
    const int wv   = __builtin_amdgcn_readfirstlane(threadIdx.x >> 6);
    int q = blockIdx.x * 4 + wv;
    if (q >= total) q = total - 1;   // clamp: barriers stay block-uniform
    const int b    = q / n;
    const int base = b * n;

    const float qx = new_xyz[q * 3 + 0];
    const float qy = new_xyz[q * 3 + 1];
    const float qz = new_xyz[q * 3 + 2];

    // neighbor cell ranges (margin: boundary rounding can never drop a hit)
    int cx0 = max((int)floorf((qx - 2.0f - MARGIN) * INV_CELL), 0);
    int cx1 = min((int)floorf((qx + 2.0f + MARGIN) * INV_CELL), GD - 1);
    int cy0 = max((int)floorf((qy - 2.0f - MARGIN) * INV_CELL), 0);
    int cy1 = min((int)floorf((qy + 2.0f + MARGIN) * INV_CELL), GD - 1);
    int cz0 = max((int)floorf((qz - 2.0f - MARGIN) * INV_CELL), 0);
    int cz1 = min((int)floorf((qz + 2.0f + MARGIN) * INV_CELL), GD - 1);
    const int ny = cy1 - cy0 + 1;
    const int nrange = __builtin_amdgcn_readfirstlane((cx1 - cx0 + 1) * ny); // <= 16

    // lane r (< nrange): contiguous z-column range [s0, s1) in the CSR
    int cc = 0, gb = 0;
    if (lane < nrange) {
        int rx  = lane / ny;
        int ry  = lane - rx * ny;
        int col = ((b * GD + (cx0 + rx)) * GD + (cy0 + ry)) * GD;
        int s0  = cellStart[col + cz0];
        int s1  = cellStart[col + cz1 + 1];
        gb = s0;
        cc = s1 - s0;
    }
    // 64-wide inclusive scan (lanes >= nrange carry 0 -> run == T sentinel)
    int run = cc;
    #pragma unroll
    for (int off = 1; off < 64; off <<= 1) {
        int y = __shfl_up(run, off, 64);
        if (lane >= off) run += y;
    }
    const int T = __shfl(run, nrange - 1, 64);

    if (lane < 16) spref[wv][lane + 1] = run;   // entries nrange..16 == T
    if (lane == 0) spref[wv][0] = 0;
    if (lane < nrange) sgb[wv][lane] = gb;

    __syncthreads();   // fence: prefix/base writes (lane X) -> reads (lane Y)

    // scan chunks: lane -> range via 4-step branchless binary search
    int tot = 0;
    for (int r = 0; r < T; r += 64) {
        const int  t   = r + lane;
        const bool act = t < T;
        const int  tcl = act ? t : 0;
        int k = 0;
        #pragma unroll
        for (int step = 8; step >= 1; step >>= 1) {
            const int nk = k + step;
            if (spref[wv][nk] <= tcl) k = nk;   // largest k with spref[k] <= t
        }
        const int ai = sgb[wv][k] + (tcl - spref[wv][k]);
        const float4 f = pts[ai];
        float dx = qx - f.x, dy = qy - f.y, dz = qz - f.z;
        float d2 = (dx * dx + dy * dy) + dz * dz;     // numpy rounding order
        const bool hit = act && (d2 < 4.0f);          // RADIUS^2
        const unsigned long long m = __ballot(hit);
        const int pos = tot + __builtin_amdgcn_mbcnt_hi(
            (unsigned)(m >> 32), __builtin_amdgcn_mbcnt_lo((unsigned)m, 0u));
        if (hit && pos < 64) slist[wv][pos] = __float_as_int(f.w);
        tot += __popcll(m);
    }

    __syncthreads();   // fence: slist writes (lane X) -> slist reads (lane Y)

    // sort hit indices ascending (pad INT_MAX); width-32 fast path (uniform)
    const int totv = tot < 64 ? tot : 64;
    int v = (lane < totv) ? slist[wv][lane] : 0x7fffffff;
    const int l32 = lane & 31;
    if (totv <= 32) {
        #pragma unroll
        for (int k = 2; k <= 32; k <<= 1) {
            #pragma unroll
            for (int j = k >> 1; j >= 1; j >>= 1) {
                const int  o     = __shfl_xor(v, j, 32);
                const bool up    = ((l32 & k) == 0);
                const bool lower = ((l32 & j) == 0);
                const int  mn = v < o ? v : o;
                const int  mx = v < o ? o : v;
                v = (lower == up) ? mn : mx;
            }
        }
    } else {
        #pragma unroll
        for (int k = 2; k <= 64; k <<= 1) {
            #pragma unroll
            for (int j = k >> 1; j >= 1; j >>= 1) {
                const int  o     = __shfl_xor(v, j, 64);
                const bool up    = ((lane & k) == 0);
                const bool lower = ((lane & j) == 0);
                const int  mn = v < o ? v : o;
                const int  mx = v < o ? o : v;
                v = (lower == up) ? mn : mx;
            }
        }
    }

    const int tc     = tot < NS ? tot : NS;
    const int firstv = __shfl(v, 0, 64);
    const int first  = (tot > 0) ? firstv : (n - 1);  // ref: idx==n gather clamps
    const int s      = lane & 31;
    const int jl0    = __shfl(v, s, 64);              // s <= 31: low-half source
    const int jl     = (s < tc) ? jl0 : first;

    // weights
    const int tcm = tc > 0 ? tc : 1;
    if (lane < NS)
        wout[(size_t)q * NS + lane] = (lane < tcm) ? 1.0f / (float)tcm : 0.0f;

    // grouped relation: half-wave 0 -> pred/out0, half-wave 1 -> tgt/out1
    const float* __restrict__ src = (lane >> 5) ? tgt : pred;
    float* __restrict__ dst       = (lane >> 5) ? out1 : out0;
    const float4* __restrict__ nb = (const float4*)(src + (size_t)(base + jl) * C);
    const float4* __restrict__ ct = (const float4*)(src + (size_t)q * C);
    float* __restrict__ o = dst + (size_t)q * (C * NS) + s;
    #pragma unroll
    for (int c4 = 0; c4 < C / 4; ++c4) {
        const float4 a = nb[c4], bq = ct[c4];
        o[(c4 * 4 + 0) * NS] = a.x - bq.x;
        o[(c4 * 4 + 1) * NS] = a.y - bq.y;
        o[(c4 * 4 + 2) * NS] = a.z - bq.z;
        o[(c4 * 4 + 3) * NS] = a.w - bq.w;
    }
    #pragma unroll
    for (int c = (C / 4) * 4; c < C; ++c)   // dead for C=20
        o[c * NS] = src[(size_t)(base + jl) * C + c] - src[(size_t)q * C + c];
}

// ---------------------------------------------------------------------------
// Fallback: fused brute-force (used only if ws/shape preconditions fail).
// Deterministic (no atomics, no workspace).
// ---------------------------------------------------------------------------
template <int C>
__global__ __launch_bounds__(256) void fused_brute_kernel(
    const float* __restrict__ xyz, const float* __restrict__ new_xyz,
    const float* __restrict__ pred, const float* __restrict__ tgt,
    int n, int total, float* __restrict__ out0, float* __restrict__ out1,
    float* __restrict__ wout)
{
#pragma clang fp contract(off)
    __shared__ int sidx[8][NS];

    const int lane = threadIdx.x & 63;
    const int wv   = __builtin_amdgcn_readfirstlane(threadIdx.x >> 6);
    int q0 = (blockIdx.x * 4 + wv) * 2;
    if (q0 > total - 2) q0 = total - 2;
    const int base = (q0 / n) * n;

    const float ax0 = new_xyz[q0 * 3 + 0], ay0 = new_xyz[q0 * 3 + 1], az0 = new_xyz[q0 * 3 + 2];
    const float ax1 = new_xyz[q0 * 3 + 3], ay1 = new_xyz[q0 * 3 + 4], az1 = new_xyz[q0 * 3 + 5];
    const float* __restrict__ px = xyz + (size_t)base * 3;

    int tot0 = 0, tot1 = 0, first0 = n - 1, first1 = n - 1;
    for (int it = 0; it < n; it += 64) {
        const int ja  = it + lane;
        const int jca = ja < n ? ja : n - 1;
        const float xa = px[jca * 3 + 0], ya = px[jca * 3 + 1], za = px[jca * 3 + 2];
        float dx = ax0 - xa, dy = ay0 - ya, dz = az0 - za;
        const float d0 = (dx * dx + dy * dy) + dz * dz;
        dx = ax1 - xa; dy = ay1 - ya; dz = az1 - za;
        const float d1 = (dx * dx + dy * dy) + dz * dz;
        const bool h0 = (ja < n) & (d0 < 4.0f);
        const bool h1 = (ja < n) & (d1 < 4.0f);
        const unsigned long long m0 = __ballot(h0);
        if (m0) {
            if (tot0 == 0) first0 = it + __builtin_ctzll(m0);
            const int pos = tot0 + __builtin_amdgcn_mbcnt_hi(
                (unsigned)(m0 >> 32), __builtin_amdgcn_mbcnt_lo((unsigned)m0, 0u));
            if (h0 && pos < NS) sidx[wv * 2 + 0][pos] = ja;
            tot0 += __popcll(m0);
        }
        const unsigned long long m1 = __ballot(h1);
        if (m1) {
            if (tot1 == 0) first1 = it + __builtin_ctzll(m1);
            const int pos = tot1 + __builtin_amdgcn_mbcnt_hi(
                (unsigned)(m1 >> 32), __builtin_amdgcn_mbcnt_lo((unsigned)m1, 0u));
            if (h1 && pos < NS) sidx[wv * 2 + 1][pos] = ja;
            tot1 += __popcll(m1);
        }
    }

    const int s  = lane & 31;
    const int qs = lane >> 5;
    {
        const int tt    = qs ? tot1 : tot0;
        const int first = qs ? first1 : first0;
        const int tc    = tt < NS ? tt : NS;
        if (s >= tc) sidx[wv * 2 + qs][s] = first;
        const int tcm = tc > 0 ? tc : 1;
        wout[(size_t)q0 * NS + lane] = (s < tcm) ? 1.0f / (float)tcm : 0.0f;
    }
    __syncthreads();

    const int q  = q0 + qs;
    const int jl = sidx[wv * 2 + qs][s];
    const float4* __restrict__ nb_p = (const float4*)(pred + (size_t)(base + jl) * C);
    const float4* __restrict__ nb_t = (const float4*)(tgt  + (size_t)(base + jl) * C);
    const float4* __restrict__ ct_p = (const float4*)(pred + (size_t)q * C);
    const float4* __restrict__ ct_t = (const float4*)(tgt  + (size_t)q * C);
    float* __restrict__ o0 = out0 + (size_t)q * (C * NS) + s;
    float* __restrict__ o1 = out1 + (size_t)q * (C * NS) + s;
    #pragma unroll
    for (int c4 = 0; c4 < C / 4; ++c4) {
        const float4 a = nb_p[c4], bq = ct_p[c4];
        o0[(c4 * 4 + 0) * NS] = a.x - bq.x;
        o0[(c4 * 4 + 1) * NS] = a.y - bq.y;
        o0[(c4 * 4 + 2) * NS] = a.z - bq.z;
        o0[(c4 * 4 + 3) * NS] = a.w - bq.w;
        const float4 u = nb_t[c4], vv = ct_t[c4];
        o1[(c4 * 4 + 0) * NS] = u.x - vv.x;
        o1[(c4 * 4 + 1) * NS] = u.y - vv.y;
        o1[(c4 * 4 + 2) * NS] = u.z - vv.z;
        o1[(c4 * 4 + 3) * NS] = u.w - vv.w;
    }
}

// ---------------------------------------------------------------------------
extern "C" void kernel_launch(void* const* d_in, const int* in_sizes, int n_in,
                              void* d_out, int out_size, void* d_ws, size_t ws_size,
                              hipStream_t stream)
{
    const float* xyz     = (const float*)d_in[0];
    const float* pred    = (const float*)d_in[2];
    const float* tgt     = (const float*)d_in[3];
    const float* new_xyz = (const float*)d_in[4];

    const int total = in_sizes[0] / 3;     // 16384
    const int nb    = in_sizes[1];         // 4
    const int n     = total / nb;          // 4096
    const int C     = in_sizes[2] / total; // 20

    float* out = (float*)d_out;
    const size_t relsz = (size_t)total * C * NS;
    float* out0 = out;
    float* out1 = out + relsz;
    float* wout = out + 2 * relsz;

    const size_t ws_need = (size_t)total * sizeof(float4)
                         + ((size_t)nb * NC3 + 1) * sizeof(int);

    if (C == 20 && n == NPB && ws_size >= ws_need) {
        float4* pts       = (float4*)d_ws;   // 16B-aligned base
        int*    cellStart = (int*)((char*)d_ws + (size_t)total * sizeof(float4));

        bin_sort_kernel<<<nb, 256, 0, stream>>>(xyz, n, nb, cellStart, pts);
        query_kernel<20><<<(total + 3) / 4, 256, 0, stream>>>(
            new_xyz, pred, tgt, cellStart, pts, n, total, out0, out1, wout);
    } else if (C == 20) {
        fused_brute_kernel<20><<<(total + 7) / 8, 256, 0, stream>>>(
            xyz, new_xyz, pred, tgt, n, total, out0, out1, wout);
    }
    (void)n_in; (void)out_size;
}

// Round 12
// 47.707 us; speedup vs baseline: 1.0821x; 1.0821x over previous
//
#include <hip/hip_runtime.h>

#define NS 32
#define GD 10
#define NC3 (GD * GD * GD)
#define INV_CELL 0.5f
#define MARGIN 1e-3f

// ---------------------------------------------------------------------------
// CSR build, parallel (r11's 4-block fused builder was the regression):
//   memset(cnt) -> count (64 blk, global atomics) -> scan (1 blk/batch)
//   -> scatter (64 blk, atomic cursors) -> per-cell sort by index.
// The per-cell sort erases atomic ordering, so the CSR is a pure function of
// the inputs (harness graph-replays and re-validates -> determinism needed).
// ---------------------------------------------------------------------------
__global__ __launch_bounds__(256) void count_kernel(
    const float* __restrict__ xyz, int n, int total, int* __restrict__ cnt)
{
    int i = blockIdx.x * 256 + threadIdx.x;
    if (i >= total) return;
    int b = i / n;
    float x = xyz[3 * i], y = xyz[3 * i + 1], z = xyz[3 * i + 2];
    int cx = min(max((int)floorf(x * INV_CELL), 0), GD - 1);
    int cy = min(max((int)floorf(y * INV_CELL), 0), GD - 1);
    int cz = min(max((int)floorf(z * INV_CELL), 0), GD - 1);
    atomicAdd(&cnt[b * NC3 + (cx * GD + cy) * GD + cz], 1);
}

__global__ __launch_bounds__(256) void scan_kernel(
    const int* __restrict__ cnt, int n, int nb,
    int* __restrict__ cellStart, int* __restrict__ cur)
{
    __shared__ int wsum[4];
    const int tid  = threadIdx.x;
    const int b    = blockIdx.x;
    const int base = tid * 4;

    int c0 = 0, c1 = 0, c2 = 0, c3 = 0, tt = 0;
    if (base < NC3) {
        c0 = cnt[b * NC3 + base];
        c1 = base + 1 < NC3 ? cnt[b * NC3 + base + 1] : 0;
        c2 = base + 2 < NC3 ? cnt[b * NC3 + base + 2] : 0;
        c3 = base + 3 < NC3 ? cnt[b * NC3 + base + 3] : 0;
        tt = c0 + c1 + c2 + c3;
    }
    const int lane = tid & 63, wv = tid >> 6;
    int run = tt;
    #pragma unroll
    for (int off = 1; off < 64; off <<= 1) {
        int y = __shfl_up(run, off, 64);
        if (lane >= off) run += y;
    }
    if (lane == 63) wsum[wv] = run;
    __syncthreads();
    int woff = 0;
    for (int w = 0; w < wv; ++w) woff += wsum[w];
    const int excl = woff + run - tt;
    if (base < NC3) {
        const int g = b * n + excl;
        cellStart[b * NC3 + base] = g;              cur[b * NC3 + base] = g;
        if (base + 1 < NC3) { cellStart[b * NC3 + base + 1] = g + c0;           cur[b * NC3 + base + 1] = g + c0; }
        if (base + 2 < NC3) { cellStart[b * NC3 + base + 2] = g + c0 + c1;      cur[b * NC3 + base + 2] = g + c0 + c1; }
        if (base + 3 < NC3) { cellStart[b * NC3 + base + 3] = g + c0 + c1 + c2; cur[b * NC3 + base + 3] = g + c0 + c1 + c2; }
    }
    if (b == nb - 1 && tid == 0) cellStart[nb * NC3] = nb * n;
}

__global__ __launch_bounds__(256) void scatter_kernel(
    const float* __restrict__ xyz, int n, int total,
    int* __restrict__ cur, float4* __restrict__ pts)
{
    int i = blockIdx.x * 256 + threadIdx.x;
    if (i >= total) return;
    int b  = i / n;
    int il = i - b * n;
    float x = xyz[3 * i], y = xyz[3 * i + 1], z = xyz[3 * i + 2];
    int cx = min(max((int)floorf(x * INV_CELL), 0), GD - 1);
    int cy = min(max((int)floorf(y * INV_CELL), 0), GD - 1);
    int cz = min(max((int)floorf(z * INV_CELL), 0), GD - 1);
    int pos = atomicAdd(&cur[b * NC3 + (cx * GD + cy) * GD + cz], 1);
    pts[pos] = make_float4(x, y, z, __int_as_float(il));
}

// Per-cell sort by point index (ascending). 8 cells/block, half-wave each,
// width-32 bitonic (cells are Poisson(~4); serial fallback if >32, P~0 but
// structurally unbounded in CSR).
__global__ __launch_bounds__(256) void sort_cells_kernel(
    const int* __restrict__ cellStart, float4* __restrict__ pts, int ncells)
{
    const int half = threadIdx.x >> 5;
    const int l32  = threadIdx.x & 31;
    const int cell = blockIdx.x * 8 + half;
    if (cell >= ncells) return;
    const int s0 = cellStart[cell];
    const int e  = cellStart[cell + 1];
    const int cc = e - s0;
    if (cc <= 1) return;

    if (cc <= 32) {
        float4 f = make_float4(0.f, 0.f, 0.f, 0.f);
        int key = 0x7fffffff;
        if (l32 < cc) {
            f   = pts[s0 + l32];
            key = __float_as_int(f.w);        // local idx (bit roundtrip, >= 0)
        }
        int src = l32;
        #pragma unroll
        for (int k = 2; k <= 32; k <<= 1) {
            #pragma unroll
            for (int j = k >> 1; j >= 1; j >>= 1) {
                const int  ok    = __shfl_xor(key, j, 32);
                const int  os    = __shfl_xor(src, j, 32);
                const bool up    = ((l32 & k) == 0);
                const bool lower = ((l32 & j) == 0);
                const bool takeMin = (lower == up);
                const bool keep = takeMin ? (key <= ok) : (key >= ok);
                key = keep ? key : ok;
                src = keep ? src : os;
            }
        }
        const float sx = __shfl(f.x, src, 32);
        const float sy = __shfl(f.y, src, 32);
        const float sz = __shfl(f.z, src, 32);
        const float sw = __shfl(f.w, src, 32);
        if (l32 < cc) pts[s0 + l32] = make_float4(sx, sy, sz, sw);
    } else if (l32 == 0) {
        for (int i = s0 + 1; i < e; ++i) {    // deterministic serial fallback
            float4 kf = pts[i];
            int kk = __float_as_int(kf.w);
            int j = i - 1;
            while (j >= s0 && __float_as_int(pts[j].w) > kk) {
                pts[j + 1] = pts[j];
                --j;
            }
            pts[j + 1] = kf;
        }
    }
}

// ---------------------------------------------------------------------------
// K2: fused query + weight + grouped relation. One wave per query.
// (Bit-identical to the passing r11 kernel.)
//  1. neighbor region = nx*ny <= 16 CONTIGUOUS z-column ranges in the CSR;
//     lanes load ranges in parallel; 64-wide shfl-scan; prefix+bases -> LDS.
//  [barrier]
//  2. scan ceil(T/64) chunks; lane -> (range, slot) via 4-step binary search;
//     float4 gather -> d2 -> ballot-compact hits.
//  [barrier]
//  3. bitonic sort ascending (width-32 fast path when tot <= 32) -> first 32
//     by index; pad with first; n-1 row if none.
//  4. lanes 0-31 emit pred relation (+weights), lanes 32-63 tgt relation.
// ---------------------------------------------------------------------------
template <int C>
__global__ __launch_bounds__(256) void query_kernel(
    const float* __restrict__ new_xyz,
    const float* __restrict__ pred, const float* __restrict__ tgt,
    const int* __restrict__ cellStart, const float4* __restrict__ pts,
    int n, int total,
    float* __restrict__ out0, float* __restrict__ out1, float* __restrict__ wout)
{
#pragma clang fp contract(off)
    __shared__ int spref[4][17];
    __shared__ int sgb[4][16];
    __shared__ int slist[4][64];

    const int lane = threadIdx.x & 63;
    const int wv   = __builtin_amdgcn_readfirstlane(threadIdx.x >> 6);
    int q = blockIdx.x * 4 + wv;
    if (q >= total) q = total - 1;   // clamp: barriers stay block-uniform
    const int b    = q / n;
    const int base = b * n;

    const float qx = new_xyz[q * 3 + 0];
    const float qy = new_xyz[q * 3 + 1];
    const float qz = new_xyz[q * 3 + 2];

    int cx0 = max((int)floorf((qx - 2.0f - MARGIN) * INV_CELL), 0);
    int cx1 = min((int)floorf((qx + 2.0f + MARGIN) * INV_CELL), GD - 1);
    int cy0 = max((int)floorf((qy - 2.0f - MARGIN) * INV_CELL), 0);
    int cy1 = min((int)floorf((qy + 2.0f + MARGIN) * INV_CELL), GD - 1);
    int cz0 = max((int)floorf((qz - 2.0f - MARGIN) * INV_CELL), 0);
    int cz1 = min((int)floorf((qz + 2.0f + MARGIN) * INV_CELL), GD - 1);
    const int ny = cy1 - cy0 + 1;
    const int nrange = __builtin_amdgcn_readfirstlane((cx1 - cx0 + 1) * ny); // <= 16

    int cc = 0, gb = 0;
    if (lane < nrange) {
        int rx  = lane / ny;
        int ry  = lane - rx * ny;
        int col = ((b * GD + (cx0 + rx)) * GD + (cy0 + ry)) * GD;
        int s0  = cellStart[col + cz0];
        int s1  = cellStart[col + cz1 + 1];
        gb = s0;
        cc = s1 - s0;
    }
    int run = cc;
    #pragma unroll
    for (int off = 1; off < 64; off <<= 1) {
        int y = __shfl_up(run, off, 64);
        if (lane >= off) run += y;
    }
    const int T = __shfl(run, nrange - 1, 64);

    if (lane < 16) spref[wv][lane + 1] = run;   // entries nrange..16 == T
    if (lane == 0) spref[wv][0] = 0;
    if (lane < nrange) sgb[wv][lane] = gb;

    __syncthreads();   // fence: prefix/base writes (lane X) -> reads (lane Y)

    int tot = 0;
    for (int r = 0; r < T; r += 64) {
        const int  t   = r + lane;
        const bool act = t < T;
        const int  tcl = act ? t : 0;
        int k = 0;
        #pragma unroll
        for (int step = 8; step >= 1; step >>= 1) {
            const int nk = k + step;
            if (spref[wv][nk] <= tcl) k = nk;   // largest k with spref[k] <= t
        }
        const int ai = sgb[wv][k] + (tcl - spref[wv][k]);
        const float4 f = pts[ai];
        float dx = qx - f.x, dy = qy - f.y, dz = qz - f.z;
        float d2 = (dx * dx + dy * dy) + dz * dz;     // numpy rounding order
        const bool hit = act && (d2 < 4.0f);          // RADIUS^2
        const unsigned long long m = __ballot(hit);
        const int pos = tot + __builtin_amdgcn_mbcnt_hi(
            (unsigned)(m >> 32), __builtin_amdgcn_mbcnt_lo((unsigned)m, 0u));
        if (hit && pos < 64) slist[wv][pos] = __float_as_int(f.w);
        tot += __popcll(m);
    }

    __syncthreads();   // fence: slist writes (lane X) -> slist reads (lane Y)

    const int totv = tot < 64 ? tot : 64;
    int v = (lane < totv) ? slist[wv][lane] : 0x7fffffff;
    const int l32 = lane & 31;
    if (totv <= 32) {
        #pragma unroll
        for (int k = 2; k <= 32; k <<= 1) {
            #pragma unroll
            for (int j = k >> 1; j >= 1; j >>= 1) {
                const int  o     = __shfl_xor(v, j, 32);
                const bool up    = ((l32 & k) == 0);
                const bool lower = ((l32 & j) == 0);
                const int  mn = v < o ? v : o;
                const int  mx = v < o ? o : v;
                v = (lower == up) ? mn : mx;
            }
        }
    } else {
        #pragma unroll
        for (int k = 2; k <= 64; k <<= 1) {
            #pragma unroll
            for (int j = k >> 1; j >= 1; j >>= 1) {
                const int  o     = __shfl_xor(v, j, 64);
                const bool up    = ((lane & k) == 0);
                const bool lower = ((lane & j) == 0);
                const int  mn = v < o ? v : o;
                const int  mx = v < o ? o : v;
                v = (lower == up) ? mn : mx;
            }
        }
    }

    const int tc     = tot < NS ? tot : NS;
    const int firstv = __shfl(v, 0, 64);
    const int first  = (tot > 0) ? firstv : (n - 1);  // ref: idx==n gather clamps
    const int s      = lane & 31;
    const int jl0    = __shfl(v, s, 64);              // s <= 31: low-half source
    const int jl     = (s < tc) ? jl0 : first;

    const int tcm = tc > 0 ? tc : 1;
    if (lane < NS)
        wout[(size_t)q * NS + lane] = (lane < tcm) ? 1.0f / (float)tcm : 0.0f;

    const float* __restrict__ src = (lane >> 5) ? tgt : pred;
    float* __restrict__ dst       = (lane >> 5) ? out1 : out0;
    const float4* __restrict__ nb = (const float4*)(src + (size_t)(base + jl) * C);
    const float4* __restrict__ ct = (const float4*)(src + (size_t)q * C);
    float* __restrict__ o = dst + (size_t)q * (C * NS) + s;
    #pragma unroll
    for (int c4 = 0; c4 < C / 4; ++c4) {
        const float4 a = nb[c4], bq = ct[c4];
        o[(c4 * 4 + 0) * NS] = a.x - bq.x;
        o[(c4 * 4 + 1) * NS] = a.y - bq.y;
        o[(c4 * 4 + 2) * NS] = a.z - bq.z;
        o[(c4 * 4 + 3) * NS] = a.w - bq.w;
    }
    #pragma unroll
    for (int c = (C / 4) * 4; c < C; ++c)   // dead for C=20
        o[c * NS] = src[(size_t)(base + jl) * C + c] - src[(size_t)q * C + c];
}

// ---------------------------------------------------------------------------
// Fallback: fused brute-force (used only if ws/shape preconditions fail).
// ---------------------------------------------------------------------------
template <int C>
__global__ __launch_bounds__(256) void fused_brute_kernel(
    const float* __restrict__ xyz, const float* __restrict__ new_xyz,
    const float* __restrict__ pred, const float* __restrict__ tgt,
    int n, int total, float* __restrict__ out0, float* __restrict__ out1,
    float* __restrict__ wout)
{
#pragma clang fp contract(off)
    __shared__ int sidx[8][NS];

    const int lane = threadIdx.x & 63;
    const int wv   = __builtin_amdgcn_readfirstlane(threadIdx.x >> 6);
    int q0 = (blockIdx.x * 4 + wv) * 2;
    if (q0 > total - 2) q0 = total - 2;
    const int base = (q0 / n) * n;

    const float ax0 = new_xyz[q0 * 3 + 0], ay0 = new_xyz[q0 * 3 + 1], az0 = new_xyz[q0 * 3 + 2];
    const float ax1 = new_xyz[q0 * 3 + 3], ay1 = new_xyz[q0 * 3 + 4], az1 = new_xyz[q0 * 3 + 5];
    const float* __restrict__ px = xyz + (size_t)base * 3;

    int tot0 = 0, tot1 = 0, first0 = n - 1, first1 = n - 1;
    for (int it = 0; it < n; it += 64) {
        const int ja  = it + lane;
        const int jca = ja < n ? ja : n - 1;
        const float xa = px[jca * 3 + 0], ya = px[jca * 3 + 1], za = px[jca * 3 + 2];
        float dx = ax0 - xa, dy = ay0 - ya, dz = az0 - za;
        const float d0 = (dx * dx + dy * dy) + dz * dz;
        dx = ax1 - xa; dy = ay1 - ya; dz = az1 - za;
        const float d1 = (dx * dx + dy * dy) + dz * dz;
        const bool h0 = (ja < n) & (d0 < 4.0f);
        const bool h1 = (ja < n) & (d1 < 4.0f);
        const unsigned long long m0 = __ballot(h0);
        if (m0) {
            if (tot0 == 0) first0 = it + __builtin_ctzll(m0);
            const int pos = tot0 + __builtin_amdgcn_mbcnt_hi(
                (unsigned)(m0 >> 32), __builtin_amdgcn_mbcnt_lo((unsigned)m0, 0u));
            if (h0 && pos < NS) sidx[wv * 2 + 0][pos] = ja;
            tot0 += __popcll(m0);
        }
        const unsigned long long m1 = __ballot(h1);
        if (m1) {
            if (tot1 == 0) first1 = it + __builtin_ctzll(m1);
            const int pos = tot1 + __builtin_amdgcn_mbcnt_hi(
                (unsigned)(m1 >> 32), __builtin_amdgcn_mbcnt_lo((unsigned)m1, 0u));
            if (h1 && pos < NS) sidx[wv * 2 + 1][pos] = ja;
            tot1 += __popcll(m1);
        }
    }

    const int s  = lane & 31;
    const int qs = lane >> 5;
    {
        const int tt    = qs ? tot1 : tot0;
        const int first = qs ? first1 : first0;
        const int tc    = tt < NS ? tt : NS;
        if (s >= tc) sidx[wv * 2 + qs][s] = first;
        const int tcm = tc > 0 ? tc : 1;
        wout[(size_t)q0 * NS + lane] = (s < tcm) ? 1.0f / (float)tcm : 0.0f;
    }
    __syncthreads();

    const int q  = q0 + qs;
    const int jl = sidx[wv * 2 + qs][s];
    const float4* __restrict__ nb_p = (const float4*)(pred + (size_t)(base + jl) * C);
    const float4* __restrict__ nb_t = (const float4*)(tgt  + (size_t)(base + jl) * C);
    const float4* __restrict__ ct_p = (const float4*)(pred + (size_t)q * C);
    const float4* __restrict__ ct_t = (const float4*)(tgt  + (size_t)q * C);
    float* __restrict__ o0 = out0 + (size_t)q * (C * NS) + s;
    float* __restrict__ o1 = out1 + (size_t)q * (C * NS) + s;
    #pragma unroll
    for (int c4 = 0; c4 < C / 4; ++c4) {
        const float4 a = nb_p[c4], bq = ct_p[c4];
        o0[(c4 * 4 + 0) * NS] = a.x - bq.x;
        o0[(c4 * 4 + 1) * NS] = a.y - bq.y;
        o0[(c4 * 4 + 2) * NS] = a.z - bq.z;
        o0[(c4 * 4 + 3) * NS] = a.w - bq.w;
        const float4 u = nb_t[c4], vv = ct_t[c4];
        o1[(c4 * 4 + 0) * NS] = u.x - vv.x;
        o1[(c4 * 4 + 1) * NS] = u.y - vv.y;
        o1[(c4 * 4 + 2) * NS] = u.z - vv.z;
        o1[(c4 * 4 + 3) * NS] = u.w - vv.w;
    }
}

// ---------------------------------------------------------------------------
extern "C" void kernel_launch(void* const* d_in, const int* in_sizes, int n_in,
                              void* d_out, int out_size, void* d_ws, size_t ws_size,
                              hipStream_t stream)
{
    const float* xyz     = (const float*)d_in[0];
    const float* pred    = (const float*)d_in[2];
    const float* tgt     = (const float*)d_in[3];
    const float* new_xyz = (const float*)d_in[4];

    const int total = in_sizes[0] / 3;     // 16384
    const int nb    = in_sizes[1];         // 4
    const int n     = total / nb;          // 4096
    const int C     = in_sizes[2] / total; // 20

    float* out = (float*)d_out;
    const size_t relsz = (size_t)total * C * NS;
    float* out0 = out;
    float* out1 = out + relsz;
    float* wout = out + 2 * relsz;

    const int ncells = nb * NC3;
    const size_t ws_need = (size_t)total * sizeof(float4)
                         + (size_t)(3 * ncells + 1) * sizeof(int);

    if (C == 20 && ws_size >= ws_need) {
        float4* pts       = (float4*)d_ws;
        int*    cellStart = (int*)((char*)d_ws + (size_t)total * sizeof(float4));
        int*    cnt       = cellStart + (ncells + 1);
        int*    cur       = cnt + ncells;

        hipMemsetAsync(cnt, 0, (size_t)ncells * sizeof(int), stream);
        count_kernel<<<(total + 255) / 256, 256, 0, stream>>>(xyz, n, total, cnt);
        scan_kernel<<<nb, 256, 0, stream>>>(cnt, n, nb, cellStart, cur);
        scatter_kernel<<<(total + 255) / 256, 256, 0, stream>>>(xyz, n, total, cur, pts);
        sort_cells_kernel<<<(ncells + 7) / 8, 256, 0, stream>>>(cellStart, pts, ncells);
        query_kernel<20><<<(total + 3) / 4, 256, 0, stream>>>(
            new_xyz, pred, tgt, cellStart, pts, n, total, out0, out1, wout);
    } else if (C == 20) {
        fused_brute_kernel<20><<<(total + 7) / 8, 256, 0, stream>>>(
            xyz, new_xyz, pred, tgt, n, total, out0, out1, wout);
    }
    (void)n_in; (void)out_size;
}

// Round 13
// 37.169 us; speedup vs baseline: 1.3889x; 1.2835x over previous
//
#include <hip/hip_runtime.h>

#define NS 32
#define GD 10
#define NCXY (GD * GD)     // z-columns per batch
#define COLCAP 128         // padded points per column (lambda ~ 41; P(>128) ~ 0)
#define WCAP 64            // per-wave hit cap in build (lambda ~ 10.25)
#define INV_CELL 0.5f
#define MARGIN 1e-3f

static __device__ __forceinline__ int lane_rank(unsigned long long m) {
    return __builtin_amdgcn_mbcnt_hi((unsigned)(m >> 32),
                                     __builtin_amdgcn_mbcnt_lo((unsigned)m, 0u));
}

// ---------------------------------------------------------------------------
// K1: single-kernel deterministic column build (replaces r12's 5-node
// memset/count/scan/scatter/sort front-end -- dispatch overhead was the
// r12 regression). One block per (batch, cx, cy) z-column:
//   phase 1: wave w ballot-compacts its quarter of the batch's points (index
//            order) that fall in this column into an LDS list.
//   phase 2: wave 0 merges the 4 lists (concatenation = index order) and
//            stable counting-sorts by z-cell via 10-ballot passes.
//   output: pts[col*COLCAP ...] grouped by z-cell (index-sorted within),
//           colOff[col*11 + k] = intra-column start of z-cell k; [10] = h.
// No atomics anywhere -> pure function of inputs (replay-deterministic).
// ---------------------------------------------------------------------------
__global__ __launch_bounds__(256) void build_kernel(
    const float* __restrict__ xyz, int n,
    int* __restrict__ colOff, float4* __restrict__ pts)
{
    __shared__ float4 hl[4][WCAP];      // 4 KB
    __shared__ int    swcnt[4];
    __shared__ float4 merged[COLCAP];   // 2 KB

    const int col  = blockIdx.x;
    const int b    = col / NCXY;
    const int cxy  = col - b * NCXY;
    const int mycx = cxy / GD;
    const int mycy = cxy - mycx * GD;
    const int lane = threadIdx.x & 63;
    const int wv   = threadIdx.x >> 6;
    const float* __restrict__ px = xyz + (size_t)b * n * 3;

    // phase 1: compact this wave's quarter (index order preserved)
    const int per = (n + 3) >> 2;
    const int j0  = wv * per;
    const int j1  = min(j0 + per, n);
    int cnt = 0;
    for (int it = j0; it < j1; it += 64) {
        const int  j   = it + lane;
        const bool inb = j < j1;
        const int  jc  = inb ? j : 0;
        const float x = px[3 * jc], y = px[3 * jc + 1], z = px[3 * jc + 2];
        const int cx = min(max((int)floorf(x * INV_CELL), 0), GD - 1);
        const int cy = min(max((int)floorf(y * INV_CELL), 0), GD - 1);
        const bool hit = inb && (cx == mycx) && (cy == mycy);
        const unsigned long long m = __ballot(hit);
        if (m) {
            const int zc  = min(max((int)floorf(z * INV_CELL), 0), GD - 1);
            const int pos = cnt + lane_rank(m);
            if (hit && pos < WCAP)
                hl[wv][pos] = make_float4(x, y, z, __int_as_float((zc << 12) | j));
            cnt += __popcll(m);
        }
    }
    if (lane == 0) swcnt[wv] = cnt < WCAP ? cnt : WCAP;
    __syncthreads();

    // phase 2a (wave 0): merge the 4 index-ordered segments
    const int p0 = swcnt[0], p1 = p0 + swcnt[1], p2 = p1 + swcnt[2], p3 = p2 + swcnt[3];
    const int h  = p3 < COLCAP ? p3 : COLCAP;
    if (wv == 0) {
        for (int g = lane; g < h; g += 64) {
            const int w   = (g >= p0) + (g >= p1) + (g >= p2);
            const int off = g - (w == 0 ? 0 : (w == 1 ? p0 : (w == 2 ? p1 : p2)));
            merged[g] = hl[w][off];
        }
    }
    __syncthreads();   // fence: merged writes (lane X) -> ballot reads (lane Y)

    if (wv == 0) {
        // count per z-cell (stable two-pass counting sort, all in registers)
        int czc[GD];
        #pragma unroll
        for (int k = 0; k < GD; ++k) czc[k] = 0;
        for (int r = 0; r < h; r += 64) {
            const int t = r + lane;
            int zc = -1;
            if (t < h) zc = __float_as_int(merged[t].w) >> 12;
            #pragma unroll
            for (int k = 0; k < GD; ++k)
                czc[k] += __popcll(__ballot(zc == k));
        }
        int off[GD + 1];
        off[0] = 0;
        #pragma unroll
        for (int k = 0; k < GD; ++k) off[k + 1] = off[k] + czc[k];

        int cur[GD];
        #pragma unroll
        for (int k = 0; k < GD; ++k) cur[k] = off[k];

        for (int r = 0; r < h; r += 64) {
            const int t = r + lane;
            int zc = -1, pl = 0;
            float4 f = make_float4(0.f, 0.f, 0.f, 0.f);
            if (t < h) { f = merged[t]; pl = __float_as_int(f.w); zc = pl >> 12; }
            #pragma unroll
            for (int k = 0; k < GD; ++k) {
                const unsigned long long mk = __ballot(zc == k);
                if (zc == k) {
                    const int pos = cur[k] + lane_rank(mk);
                    pts[(size_t)col * COLCAP + pos] =
                        make_float4(f.x, f.y, f.z, __int_as_float(pl & 4095));
                }
                cur[k] += __popcll(mk);
            }
        }
        if (lane == 0) {
            const int bo = col * 11;
            #pragma unroll
            for (int k = 0; k < GD; ++k) colOff[bo + k] = off[k];
            colOff[bo + GD] = h;
        }
    }
}

// ---------------------------------------------------------------------------
// K2: fused query + weight + grouped relation. One wave per query.
// (r12 structure; only the range lookup changed to per-column offsets.)
//  1. neighbor region = nx*ny <= 16 columns; lane r loads its column's
//     [cz0, cz1+1) offsets -> contiguous range in the padded column slot;
//     64-wide shfl-scan; 17-entry prefix + 16 bases -> LDS.
//  [barrier]
//  2. scan ceil(T/64) chunks; lane -> (range, slot) via 4-step binary search;
//     float4 gather -> d2 -> ballot-compact hits.
//  [barrier]
//  3. bitonic sort ascending (width-32 fast path when tot <= 32) -> first 32
//     by index; pad with first; n-1 row if none.
//  4. lanes 0-31 emit pred relation (+weights), lanes 32-63 tgt relation.
// ---------------------------------------------------------------------------
template <int C>
__global__ __launch_bounds__(256) void query_kernel(
    const float* __restrict__ new_xyz,
    const float* __restrict__ pred, const float* __restrict__ tgt,
    const int* __restrict__ colOff, const float4* __restrict__ pts,
    int n, int total,
    float* __restrict__ out0, float* __restrict__ out1, float* __restrict__ wout)
{
#pragma clang fp contract(off)
    __shared__ int spref[4][17];
    __shared__ int sgb[4][16];
    __shared__ int slist[4][64];

    const int lane = threadIdx.x & 63;
    const int wv   = __builtin_amdgcn_readfirstlane(threadIdx.x >> 6);
    int q = blockIdx.x * 4 + wv;
    if (q >= total) q = total - 1;   // clamp: barriers stay block-uniform
    const int b    = q / n;
    const int base = b * n;

    const float qx = new_xyz[q * 3 + 0];
    const float qy = new_xyz[q * 3 + 1];
    const float qz = new_xyz[q * 3 + 2];

    int cx0 = max((int)floorf((qx - 2.0f - MARGIN) * INV_CELL), 0);
    int cx1 = min((int)floorf((qx + 2.0f + MARGIN) * INV_CELL), GD - 1);
    int cy0 = max((int)floorf((qy - 2.0f - MARGIN) * INV_CELL), 0);
    int cy1 = min((int)floorf((qy + 2.0f + MARGIN) * INV_CELL), GD - 1);
    int cz0 = max((int)floorf((qz - 2.0f - MARGIN) * INV_CELL), 0);
    int cz1 = min((int)floorf((qz + 2.0f + MARGIN) * INV_CELL), GD - 1);
    const int ny = cy1 - cy0 + 1;
    const int nrange = __builtin_amdgcn_readfirstlane((cx1 - cx0 + 1) * ny); // <= 16

    int cc = 0, gb = 0;
    if (lane < nrange) {
        const int rx   = lane / ny;
        const int ry   = lane - rx * ny;
        const int ccol = b * NCXY + (cx0 + rx) * GD + (cy0 + ry);
        const int o0   = colOff[ccol * 11 + cz0];
        const int o1   = colOff[ccol * 11 + cz1 + 1];
        gb = ccol * COLCAP + o0;
        cc = o1 - o0;
    }
    int run = cc;
    #pragma unroll
    for (int off = 1; off < 64; off <<= 1) {
        int y = __shfl_up(run, off, 64);
        if (lane >= off) run += y;
    }
    const int T = __shfl(run, nrange - 1, 64);

    if (lane < 16) spref[wv][lane + 1] = run;   // entries nrange..16 == T
    if (lane == 0) spref[wv][0] = 0;
    if (lane < nrange) sgb[wv][lane] = gb;

    __syncthreads();   // fence: prefix/base writes (lane X) -> reads (lane Y)

    int tot = 0;
    for (int r = 0; r < T; r += 64) {
        const int  t   = r + lane;
        const bool act = t < T;
        const int  tcl = act ? t : 0;
        int k = 0;
        #pragma unroll
        for (int step = 8; step >= 1; step >>= 1) {
            const int nk = k + step;
            if (spref[wv][nk] <= tcl) k = nk;   // largest k with spref[k] <= t
        }
        const int ai = sgb[wv][k] + (tcl - spref[wv][k]);
        const float4 f = pts[ai];
        float dx = qx - f.x, dy = qy - f.y, dz = qz - f.z;
        float d2 = (dx * dx + dy * dy) + dz * dz;     // numpy rounding order
        const bool hit = act && (d2 < 4.0f);          // RADIUS^2
        const unsigned long long m = __ballot(hit);
        const int pos = tot + lane_rank(m);
        if (hit && pos < 64) slist[wv][pos] = __float_as_int(f.w);
        tot += __popcll(m);
    }

    __syncthreads();   // fence: slist writes (lane X) -> slist reads (lane Y)

    const int totv = tot < 64 ? tot : 64;
    int v = (lane < totv) ? slist[wv][lane] : 0x7fffffff;
    const int l32 = lane & 31;
    if (totv <= 32) {
        #pragma unroll
        for (int k = 2; k <= 32; k <<= 1) {
            #pragma unroll
            for (int j = k >> 1; j >= 1; j >>= 1) {
                const int  o     = __shfl_xor(v, j, 32);
                const bool up    = ((l32 & k) == 0);
                const bool lower = ((l32 & j) == 0);
                const int  mn = v < o ? v : o;
                const int  mx = v < o ? o : v;
                v = (lower == up) ? mn : mx;
            }
        }
    } else {
        #pragma unroll
        for (int k = 2; k <= 64; k <<= 1) {
            #pragma unroll
            for (int j = k >> 1; j >= 1; j >>= 1) {
                const int  o     = __shfl_xor(v, j, 64);
                const bool up    = ((lane & k) == 0);
                const bool lower = ((lane & j) == 0);
                const int  mn = v < o ? v : o;
                const int  mx = v < o ? o : v;
                v = (lower == up) ? mn : mx;
            }
        }
    }

    const int tc     = tot < NS ? tot : NS;
    const int firstv = __shfl(v, 0, 64);
    const int first  = (tot > 0) ? firstv : (n - 1);  // ref: idx==n gather clamps
    const int s      = lane & 31;
    const int jl0    = __shfl(v, s, 64);              // s <= 31: low-half source
    const int jl     = (s < tc) ? jl0 : first;

    const int tcm = tc > 0 ? tc : 1;
    if (lane < NS)
        wout[(size_t)q * NS + lane] = (lane < tcm) ? 1.0f / (float)tcm : 0.0f;

    const float* __restrict__ src = (lane >> 5) ? tgt : pred;
    float* __restrict__ dst       = (lane >> 5) ? out1 : out0;
    const float4* __restrict__ nb = (const float4*)(src + (size_t)(base + jl) * C);
    const float4* __restrict__ ct = (const float4*)(src + (size_t)q * C);
    float* __restrict__ o = dst + (size_t)q * (C * NS) + s;
    #pragma unroll
    for (int c4 = 0; c4 < C / 4; ++c4) {
        const float4 a = nb[c4], bq = ct[c4];
        o[(c4 * 4 + 0) * NS] = a.x - bq.x;
        o[(c4 * 4 + 1) * NS] = a.y - bq.y;
        o[(c4 * 4 + 2) * NS] = a.z - bq.z;
        o[(c4 * 4 + 3) * NS] = a.w - bq.w;
    }
    #pragma unroll
    for (int c = (C / 4) * 4; c < C; ++c)   // dead for C=20
        o[c * NS] = src[(size_t)(base + jl) * C + c] - src[(size_t)q * C + c];
}

// ---------------------------------------------------------------------------
// Fallback: fused brute-force (used only if ws/shape preconditions fail).
// ---------------------------------------------------------------------------
template <int C>
__global__ __launch_bounds__(256) void fused_brute_kernel(
    const float* __restrict__ xyz, const float* __restrict__ new_xyz,
    const float* __restrict__ pred, const float* __restrict__ tgt,
    int n, int total, float* __restrict__ out0, float* __restrict__ out1,
    float* __restrict__ wout)
{
#pragma clang fp contract(off)
    __shared__ int sidx[8][NS];

    const int lane = threadIdx.x & 63;
    const int wv   = __builtin_amdgcn_readfirstlane(threadIdx.x >> 6);
    int q0 = (blockIdx.x * 4 + wv) * 2;
    if (q0 > total - 2) q0 = total - 2;
    const int base = (q0 / n) * n;

    const float ax0 = new_xyz[q0 * 3 + 0], ay0 = new_xyz[q0 * 3 + 1], az0 = new_xyz[q0 * 3 + 2];
    const float ax1 = new_xyz[q0 * 3 + 3], ay1 = new_xyz[q0 * 3 + 4], az1 = new_xyz[q0 * 3 + 5];
    const float* __restrict__ px = xyz + (size_t)base * 3;

    int tot0 = 0, tot1 = 0, first0 = n - 1, first1 = n - 1;
    for (int it = 0; it < n; it += 64) {
        const int ja  = it + lane;
        const int jca = ja < n ? ja : n - 1;
        const float xa = px[jca * 3 + 0], ya = px[jca * 3 + 1], za = px[jca * 3 + 2];
        float dx = ax0 - xa, dy = ay0 - ya, dz = az0 - za;
        const float d0 = (dx * dx + dy * dy) + dz * dz;
        dx = ax1 - xa; dy = ay1 - ya; dz = az1 - za;
        const float d1 = (dx * dx + dy * dy) + dz * dz;
        const bool h0 = (ja < n) & (d0 < 4.0f);
        const bool h1 = (ja < n) & (d1 < 4.0f);
        const unsigned long long m0 = __ballot(h0);
        if (m0) {
            if (tot0 == 0) first0 = it + __builtin_ctzll(m0);
            const int pos = tot0 + lane_rank(m0);
            if (h0 && pos < NS) sidx[wv * 2 + 0][pos] = ja;
            tot0 += __popcll(m0);
        }
        const unsigned long long m1 = __ballot(h1);
        if (m1) {
            if (tot1 == 0) first1 = it + __builtin_ctzll(m1);
            const int pos = tot1 + lane_rank(m1);
            if (h1 && pos < NS) sidx[wv * 2 + 1][pos] = ja;
            tot1 += __popcll(m1);
        }
    }

    const int s  = lane & 31;
    const int qs = lane >> 5;
    {
        const int tt    = qs ? tot1 : tot0;
        const int first = qs ? first1 : first0;
        const int tc    = tt < NS ? tt : NS;
        if (s >= tc) sidx[wv * 2 + qs][s] = first;
        const int tcm = tc > 0 ? tc : 1;
        wout[(size_t)q0 * NS + lane] = (s < tcm) ? 1.0f / (float)tcm : 0.0f;
    }
    __syncthreads();

    const int q  = q0 + qs;
    const int jl = sidx[wv * 2 + qs][s];
    const float4* __restrict__ nb_p = (const float4*)(pred + (size_t)(base + jl) * C);
    const float4* __restrict__ nb_t = (const float4*)(tgt  + (size_t)(base + jl) * C);
    const float4* __restrict__ ct_p = (const float4*)(pred + (size_t)q * C);
    const float4* __restrict__ ct_t = (const float4*)(tgt  + (size_t)q * C);
    float* __restrict__ o0 = out0 + (size_t)q * (C * NS) + s;
    float* __restrict__ o1 = out1 + (size_t)q * (C * NS) + s;
    #pragma unroll
    for (int c4 = 0; c4 < C / 4; ++c4) {
        const float4 a = nb_p[c4], bq = ct_p[c4];
        o0[(c4 * 4 + 0) * NS] = a.x - bq.x;
        o0[(c4 * 4 + 1) * NS] = a.y - bq.y;
        o0[(c4 * 4 + 2) * NS] = a.z - bq.z;
        o0[(c4 * 4 + 3) * NS] = a.w - bq.w;
        const float4 u = nb_t[c4], vv = ct_t[c4];
        o1[(c4 * 4 + 0) * NS] = u.x - vv.x;
        o1[(c4 * 4 + 1) * NS] = u.y - vv.y;
        o1[(c4 * 4 + 2) * NS] = u.z - vv.z;
        o1[(c4 * 4 + 3) * NS] = u.w - vv.w;
    }
}

// ---------------------------------------------------------------------------
extern "C" void kernel_launch(void* const* d_in, const int* in_sizes, int n_in,
                              void* d_out, int out_size, void* d_ws, size_t ws_size,
                              hipStream_t stream)
{
    const float* xyz     = (const float*)d_in[0];
    const float* pred    = (const float*)d_in[2];
    const float* tgt     = (const float*)d_in[3];
    const float* new_xyz = (const float*)d_in[4];

    const int total = in_sizes[0] / 3;     // 16384
    const int nb    = in_sizes[1];         // 4
    const int n     = total / nb;          // 4096
    const int C     = in_sizes[2] / total; // 20

    float* out = (float*)d_out;
    const size_t relsz = (size_t)total * C * NS;
    float* out0 = out;
    float* out1 = out + relsz;
    float* wout = out + 2 * relsz;

    const int ncols = nb * NCXY;
    const size_t ws_need = (size_t)ncols * COLCAP * sizeof(float4)
                         + (size_t)ncols * 11 * sizeof(int);

    if (C == 20 && ws_size >= ws_need) {
        float4* pts    = (float4*)d_ws;   // 16B-aligned base
        int*    colOff = (int*)((char*)d_ws + (size_t)ncols * COLCAP * sizeof(float4));

        build_kernel<<<ncols, 256, 0, stream>>>(xyz, n, colOff, pts);
        query_kernel<20><<<(total + 3) / 4, 256, 0, stream>>>(
            new_xyz, pred, tgt, colOff, pts, n, total, out0, out1, wout);
    } else if (C == 20) {
        fused_brute_kernel<20><<<(total + 7) / 8, 256, 0, stream>>>(
            xyz, new_xyz, pred, tgt, n, total, out0, out1, wout);
    }
    (void)n_in; (void)out_size;
}